// Round 23
// baseline (291.083 us; speedup 1.0000x reference)
//
#include <hip/hip_runtime.h>
#include <hip/hip_bf16.h>

typedef __attribute__((ext_vector_type(4))) float f32x4;
typedef __attribute__((ext_vector_type(8))) _Float16 f16x8; // MFMA f16 A/B frag
typedef unsigned short u16;

#define NB 8
#define NE 256
#define NN 4096
#define SD 64

__device__ __forceinline__ void gload_lds16(const void* g, void* l) {
  __builtin_amdgcn_global_load_lds((const __attribute__((address_space(1))) void*)g,
                                   (__attribute__((address_space(3))) void*)l, 16, 0, 0);
}
__device__ __forceinline__ float fexp2(float x) {
#if __has_builtin(__builtin_amdgcn_exp2f)
  return __builtin_amdgcn_exp2f(x);
#else
  return exp2f(x);
#endif
}

// ------- merged prep: f32->f16 input convert (bid<8192) + weight convert/transpose -------
__global__ __launch_bounds__(256) void k_prep(const float* __restrict__ x, u16* __restrict__ outF,
                                              const float* __restrict__ w, u16* __restrict__ wT) {
  int bid = blockIdx.x;
  int tid = threadIdx.x;
  if (bid < 8192) {
    int i = bid * 256 + tid;                    // float4 index < 2097152
    float4 v = reinterpret_cast<const float4*>(x)[i];
    ushort4 o;
    o.x = __builtin_bit_cast(u16, (_Float16)v.x);
    o.y = __builtin_bit_cast(u16, (_Float16)v.y);
    o.z = __builtin_bit_cast(u16, (_Float16)v.z);
    o.w = __builtin_bit_cast(u16, (_Float16)v.w);
    reinterpret_cast<ushort4*>(outF)[i] = o;
  } else {
    int i = (bid - 8192) * 256 + tid;           // < 9*256*256 = 589824
    int t = i >> 16;
    int r = i & 65535;
    int ei = r >> 8, eo = r & 255;
    int o = (t << 16) + (eo << 8) + ei;
    wT[o] = __builtin_bit_cast(u16, (_Float16)w[i]);
  }
}

// ---------------- conv 3x3 implicit GEMM, f16, halo-staged A (R14-exact, proven) ----------------
__global__ __launch_bounds__(256, 2) void k_conv(const u16* __restrict__ inF,
                                                 const u16* __restrict__ wT,
                                                 const float* __restrict__ bias,
                                                 u16* __restrict__ x1h) {
  __shared__ u16 Ahalo[264 * 64];               // 33 chunks of 1KB (slot = chunk*8 + lane>>3)
  __shared__ u16 BhL[2][128 * 64];              // B dbuf 2x16KB, swz ((eo&7)<<4)
  int b = blockIdx.x >> 6;
  int rem = blockIdx.x & 63;
  int mt = rem >> 1, et = rem & 1;
  int h0 = mt << 1;
  int tid = threadIdx.x;
  int wid = tid >> 6, lane = tid & 63;
  int wr = wid >> 1, wc = wid & 1;
  int r = lane & 15, g = lane >> 4;
  f32x4 acc[4][4];
#pragma unroll
  for (int i = 0; i < 4; ++i)
#pragma unroll
    for (int j = 0; j < 4; ++j) acc[i][j] = (f32x4){0.f, 0.f, 0.f, 0.f};
  const long ibase = (long)b * NN * NE;

  const int bsw = ((((lane & 7) << 4) ^ (((lane >> 3) & 7) << 4)) >> 1);  // f16 units
  long bSrc[4];
#pragma unroll
  for (int i = 0; i < 4; ++i) {
    int c = wid * 4 + i;
    int eo = c * 8 + (lane >> 3);
    bSrc[i] = (long)(et * 128 + eo) * 256 + bsw;
  }
  int aHalo[9];
  const u16* aSrc[9];
#pragma unroll
  for (int j = 0; j < 9; ++j) {
    int c = wid + 4 * j;
    int slot = c * 8 + (lane >> 3);
    int hr = slot >= 198 ? 3 : (slot >= 132 ? 2 : (slot >= 66 ? 1 : 0));
    int hc = slot - hr * 66;
    int ir = h0 - 1 + hr, ic = hc - 1;
    aHalo[j] = ((unsigned)ir >= 64u) | ((unsigned)ic >= 64u);
    int irc = min(max(ir, 0), 63), icc = min(max(ic, 0), 63);
    int c8s = (lane & 7) ^ (slot & 7);          // pre-swizzled ei chunk
    aSrc[j] = inF + ibase + ((long)(irc * 64 + icc) << 8) + c8s * 8;
  }

  // prologue: B(0,0) -> buf0
#pragma unroll
  for (int i = 0; i < 4; ++i)
    gload_lds16(wT + bSrc[i], (char*)BhL[0] + (wid * 4 + i) * 1024);

#pragma unroll 1
  for (int kc = 0; kc < 4; ++kc) {
    __builtin_amdgcn_s_barrier();               // all prev-kc A reads done
#pragma unroll
    for (int j = 0; j < 9; ++j) {
      int c = wid + 4 * j;
      if (c < 33)                               // wave-uniform
        gload_lds16(aSrc[j] + kc * 64, (char*)Ahalo + c * 1024);
    }
    asm volatile("s_waitcnt vmcnt(0)" ::: "memory");
#pragma unroll
    for (int j = 0; j < 9; ++j) {
      int c = wid + 4 * j;
      if (c < 33 && aHalo[j])
        *reinterpret_cast<float4*>((char*)Ahalo + c * 1024 + (lane << 4)) =
            make_float4(0.f, 0.f, 0.f, 0.f);
    }
    asm volatile("s_waitcnt lgkmcnt(0)" ::: "memory");
    __builtin_amdgcn_s_barrier();               // A(kc) visible

#pragma unroll 1
    for (int t = 0; t < 9; ++t) {
      int gidx = kc * 9 + t;
      if (t > 0) {
        asm volatile("s_waitcnt vmcnt(0)" ::: "memory");
        __builtin_amdgcn_s_barrier();
      }
      if (gidx < 35) {
        int nt = t + 1 == 9 ? 0 : t + 1;
        int nkc = t + 1 == 9 ? kc + 1 : kc;
        long tkoff = ((long)nt << 16) + nkc * 64;
        char* dstB = (char*)BhL[(gidx + 1) & 1];
#pragma unroll
        for (int i = 0; i < 4; ++i)
          gload_lds16(wT + tkoff + bSrc[i], dstB + (wid * 4 + i) * 1024);
      }
      const u16* BB = BhL[gidx & 1];
      int dy = t / 3 - 1, dx = t % 3 - 1;
      int abase = (wr + 1 + dy) * 66 + 1 + dx;  // + mi*16 + r
#pragma unroll
      for (int ks = 0; ks < 2; ++ks) {
        int c8 = ks * 4 + g;
        f16x8 ah[4], bh[4];
#pragma unroll
        for (int mi = 0; mi < 4; ++mi) {
          int slot = abase + mi * 16 + r;
          int abyte = (slot << 7) + ((c8 << 4) ^ ((slot & 7) << 4));
          ah[mi] = *reinterpret_cast<const f16x8*>(reinterpret_cast<const char*>(Ahalo) + abyte);
        }
#pragma unroll
        for (int ni = 0; ni < 4; ++ni) {
          int col = wc * 64 + ni * 16 + r;
          int bbyte = (col << 7) + ((c8 << 4) ^ ((r & 7) << 4));
          bh[ni] = *reinterpret_cast<const f16x8*>(reinterpret_cast<const char*>(BB) + bbyte);
        }
#pragma unroll
        for (int mi = 0; mi < 4; ++mi)
#pragma unroll
          for (int ni = 0; ni < 4; ++ni)
            acc[mi][ni] = __builtin_amdgcn_mfma_f32_16x16x32_f16(ah[mi], bh[ni], acc[mi][ni], 0, 0, 0);
      }
    }
  }
#pragma unroll
  for (int mi = 0; mi < 4; ++mi)
#pragma unroll
    for (int ni = 0; ni < 4; ++ni) {
      int eo = et * 128 + wc * 64 + ni * 16 + r;
      float bz = bias[eo];
#pragma unroll
      for (int i = 0; i < 4; ++i) {
        int pix = mt * 128 + wr * 64 + mi * 16 + g * 4 + i;
        float v = acc[mi][ni][i] + bz;
        long o = ibase + (long)pix * NE + eo;
        x1h[o] = __builtin_bit_cast(u16, (_Float16)v);
      }
    }
}

// ---------------- transpose x1h[b][m][e] -> x1T[b][e][m] ----------------
__global__ __launch_bounds__(256) void k_trans(const u16* __restrict__ x1h, u16* __restrict__ x1T) {
  __shared__ u16 T[64][72];
  int bid = blockIdx.x;
  int b = bid >> 8, rem = bid & 255;
  int mt = rem >> 2, et = rem & 3;
  int tid = threadIdx.x;
  for (int c = tid; c < 512; c += 256) {
    int rr = c >> 3, c8 = c & 7;
    *reinterpret_cast<float4*>(&T[rr][c8 * 8]) =
        *reinterpret_cast<const float4*>(x1h + ((long)b * NN + mt * 64 + rr) * NE + et * 64 + c8 * 8);
  }
  __syncthreads();
  for (int c = tid; c < 512; c += 256) {
    int er = c >> 3, m8 = c & 7;
    union { u16 u[8]; float4 v; } p;
#pragma unroll
    for (int j = 0; j < 8; ++j) p.u[j] = T[m8 * 8 + j][er];
    *reinterpret_cast<float4*>(x1T + ((long)b * NE + et * 64 + er) * NN + mt * 64 + m8 * 8) = p.v;
  }
}

// ---------------- fused flash attention, f16, 16x16 MFMA, V-dbuf ONE-barrier ----------------
// R22 base (early-issue, 247us) + V double-buffer: LDS 64KB (K dbuf 2x16K @0,
// V dbuf 2x16K @32K) -> bar2/vmcnt(4) before PV ELIMINATED (PV reads Vbuf(it&1),
// resident since last iteration). One barrier/iter: vmcnt(0)[K(it)+V(it) landed,
// issued a full iter ago]; bar; issue V(it+1)+K(it+1) into parity (it+1)&1 (last
// read by QK/PV(it-1), complete before bar); QK; softmax; refrag; PV (no wait).
// Occupancy unchanged (LDS-capped 2 blocks/CU). grid 512 = 8b x 64 qt; block 256;
// wave owns 16 q x 256 e. K swz ((row&15)<<4); V swz bit6 row-pair + ((e&3)<<4).
__global__ __launch_bounds__(256, 3) void k_flash7(const u16* __restrict__ x1h16,
                                                   const u16* __restrict__ x1T,
                                                   const float* __restrict__ inp,
                                                   float* __restrict__ out) {
  __shared__ char LDS[65536];
  int phys = blockIdx.x;
  int b = phys & 7;                             // batch == XCD
  int qt = phys >> 3;                           // q-tile of 64 rows (0..63)
  int tid = threadIdx.x, wid = tid >> 6, lane = tid & 63;
  int l15 = lane & 15, g4 = (lane >> 4) & 3;
  const long bN = (long)b << 12;
  const long vtb = (long)b << 20;

  // Q (f16): B-frag of S^T=mfma(K,Q): col=l15=q-row, k=g4*8+j; pre-scaled by log2e
  const long qrow = bN + qt * 64 + wid * 16 + l15;
  f16x8 qh[8];
#pragma unroll
  for (int kc = 0; kc < 8; ++kc) {
    qh[kc] = *reinterpret_cast<const f16x8*>(x1h16 + (qrow << 8) + kc * 32 + g4 * 8);
#pragma unroll
    for (int j = 0; j < 8; ++j)
      qh[kc][j] = (_Float16)((float)qh[kc][j] * 1.44269504f);
  }

  f32x4 o16[16];                                // O[16q][256e]: q=g4*4+i, e=et*16+l15
#pragma unroll
  for (int et = 0; et < 16; ++et) o16[et] = (f32x4){0.f, 0.f, 0.f, 0.f};
  float mrow = -1.0e30f, lrow = 0.f;

  // ---- staging pointers (kv0 = 0): K 16 chunks (4/thread), V 16 chunks (4/thread) ----
  const u16* kS[4];
  const u16* vS[4];
  int off[4];
#pragma unroll
  for (int i = 0; i < 4; ++i) {
    int c = wid * 4 + i;
    off[i] = c << 10;
    int kr = c * 2 + (lane >> 5);
    int kcolb = ((lane & 31) << 4) ^ ((kr & 15) << 4);
    kS[i] = x1h16 + ((bN + kr) << 8) + (kcolb >> 1);
    int rp = c * 16 + (lane >> 2);
    int e = rp ^ ((rp >> 2) & 1);               // involutive row-pair swap (bit6)
    int vcolb = ((lane & 3) << 4) ^ ((e & 3) << 4);
    vS[i] = x1T + vtb + ((long)e << 12) + (vcolb >> 1);
  }

  // per-lane constant V-read base: row l15 within e-tile + swizzles; +et*1024 per tile
  const int vbase = ((l15 << 6) ^ ((l15 & 4) << 4)) + ((g4 * 16) ^ ((l15 & 3) << 4));
  const int kxor = l15 << 4;
  // re-fragment shuffle sources: src_a = bit4(lane)*32 + l15; src_b = src_a+16; sel by bit5
  const int srcA = ((lane >> 4) & 1) * 32 + l15;
  const int srcB = srcA + 16;
  const bool hiHalf = (lane & 32) != 0;

  // ---- prologue: stage K(0) -> Kbuf0, V(0) -> Vbuf0 ----
#pragma unroll
  for (int i = 0; i < 4; ++i) { gload_lds16(kS[i], LDS + off[i]); kS[i] += 8192; }
#pragma unroll
  for (int i = 0; i < 4; ++i) { gload_lds16(vS[i], LDS + 32768 + off[i]); vS[i] += 32; }

#pragma unroll 1
  for (int it = 0; it < 128; ++it) {
    const char* KB = LDS + (it & 1) * 16384;
    const char* VB = LDS + 32768 + (it & 1) * 16384;

    asm volatile("s_waitcnt vmcnt(0)" ::: "memory");   // K(it)+V(it) landed (issued last iter)
    __builtin_amdgcn_s_barrier();                      // all waves: QK/PV(it-1) reads done
    __builtin_amdgcn_sched_barrier(0);

    // ---- issue next tile into parity (it+1)&1 (whole iteration to land) ----
    if (it < 127) {
      char* KD = LDS + ((it + 1) & 1) * 16384;
      char* VD = LDS + 32768 + ((it + 1) & 1) * 16384;
#pragma unroll
      for (int i = 0; i < 4; ++i) { gload_lds16(kS[i], KD + off[i]); kS[i] += 8192; }
#pragma unroll
      for (int i = 0; i < 4; ++i) { gload_lds16(vS[i], VD + off[i]); vS[i] += 32; }
    }

    // ---- S^T = K.Q : 2 kv-subtiles x 8 k-chunks = 16 MFMA, 2 chains ----
    f32x4 st0 = (f32x4){0.f, 0.f, 0.f, 0.f}, st1 = st0;
    int krow0 = l15 << 9, krow1 = (16 + l15) << 9;
    __builtin_amdgcn_s_setprio(1);
#pragma unroll
    for (int kc = 0; kc < 8; ++kc) {
      int kb = (kc * 64 + g4 * 16) ^ kxor;
      f16x8 k0 = *reinterpret_cast<const f16x8*>(KB + krow0 + kb);
      f16x8 k1 = *reinterpret_cast<const f16x8*>(KB + krow1 + kb);
      st0 = __builtin_amdgcn_mfma_f32_16x16x32_f16(k0, qh[kc], st0, 0, 0, 0);
      st1 = __builtin_amdgcn_mfma_f32_16x16x32_f16(k1, qh[kc], st1, 0, 0, 0);
    }
    __builtin_amdgcn_s_setprio(0);

    // ---- online softmax in log2 domain; q = l15, kv = s*16 + g4*4 + i ----
    float tmax = fmaxf(fmaxf(fmaxf(st0[0], st0[1]), fmaxf(st0[2], st0[3])),
                       fmaxf(fmaxf(st1[0], st1[1]), fmaxf(st1[2], st1[3])));
    tmax = fmaxf(tmax, __shfl_xor(tmax, 16));
    tmax = fmaxf(tmax, __shfl_xor(tmax, 32));
    if (!__all(tmax <= mrow + 11.54f)) {        // defer-max (T13), 8*log2e
      float mnew = fmaxf(mrow, tmax);
      float alpha = fexp2(mrow - mnew);
      lrow *= alpha;
      float ar[4];
#pragma unroll
      for (int i = 0; i < 4; ++i) ar[i] = __shfl(alpha, g4 * 4 + i);
#pragma unroll
      for (int et = 0; et < 16; ++et)
#pragma unroll
        for (int i = 0; i < 4; ++i) o16[et][i] *= ar[i];
      mrow = mnew;
    }
#pragma unroll
    for (int i = 0; i < 4; ++i) { st0[i] = fexp2(st0[i] - mrow); st1[i] = fexp2(st1[i] - mrow); }
    float psum = (st0[0] + st0[1]) + (st0[2] + st0[3]) + (st1[0] + st1[1]) + (st1[2] + st1[3]);
    psum += __shfl_xor(psum, 16);
    psum += __shfl_xor(psum, 32);
    lrow += psum;

    // ---- P -> f16 words; re-fragment to PV A-frag (kv = g'*8+j) via 8 shfl + selects ----
    int W0, W1, W2, W3;
    {
      unsigned a0 = __builtin_bit_cast(u16, (_Float16)st0[0]);
      unsigned a1 = __builtin_bit_cast(u16, (_Float16)st0[1]);
      unsigned a2 = __builtin_bit_cast(u16, (_Float16)st0[2]);
      unsigned a3 = __builtin_bit_cast(u16, (_Float16)st0[3]);
      unsigned b0 = __builtin_bit_cast(u16, (_Float16)st1[0]);
      unsigned b1 = __builtin_bit_cast(u16, (_Float16)st1[1]);
      unsigned b2 = __builtin_bit_cast(u16, (_Float16)st1[2]);
      unsigned b3 = __builtin_bit_cast(u16, (_Float16)st1[3]);
      W0 = (int)(a0 | (a1 << 16)); W1 = (int)(a2 | (a3 << 16));
      W2 = (int)(b0 | (b1 << 16)); W3 = (int)(b2 | (b3 << 16));
    }
    union PU { int w[4]; f16x8 v; } pa;
    {
      int u0a = __shfl(W0, srcA), u2a = __shfl(W2, srcA);
      int u1a = __shfl(W1, srcA), u3a = __shfl(W3, srcA);
      int u0b = __shfl(W0, srcB), u2b = __shfl(W2, srcB);
      int u1b = __shfl(W1, srcB), u3b = __shfl(W3, srcB);
      pa.w[0] = hiHalf ? u2a : u0a;
      pa.w[1] = hiHalf ? u3a : u1a;
      pa.w[2] = hiHalf ? u2b : u0b;
      pa.w[3] = hiHalf ? u3b : u1b;
    }

    // ---- PV: 16 e-tiles, V(it) resident in Vbuf(it&1) — no wait, no barrier ----
    __builtin_amdgcn_s_setprio(1);
#pragma unroll
    for (int et = 0; et < 16; ++et) {
      f16x8 v = *reinterpret_cast<const f16x8*>(VB + vbase + et * 1024);
      o16[et] = __builtin_amdgcn_mfma_f32_16x16x32_f16(pa.v, v, o16[et], 0, 0, 0);
    }
    __builtin_amdgcn_s_setprio(0);
  }

  // ---- epilogue: /(16*l) * inp; O: q=g4*4+i, e=et*16+l15 ----
  float linv = 1.0f / (16.0f * lrow);
  float lr[4];
#pragma unroll
  for (int i = 0; i < 4; ++i) lr[i] = __shfl(linv, g4 * 4 + i);
  const long ob = (bN + qt * 64 + wid * 16) << 8;
#pragma unroll
  for (int et = 0; et < 16; ++et)
#pragma unroll
    for (int i = 0; i < 4; ++i) {
      long off2 = ob + ((long)(g4 * 4 + i) << 8) + et * 16 + l15;
      out[off2] = o16[et][i] * lr[i] * inp[off2];
    }
}

// ---------------- host ----------------
// ws layout (bytes):
//   [0,   16M)  x1h f16
//   [16M, 32M)  x1T f16
//   [32M, 48M)  inF f16 (conv temp)
//   [48M, +1.2M) wT f16 (conv temp)
extern "C" void kernel_launch(void* const* d_in, const int* in_sizes, int n_in,
                              void* d_out, int out_size, void* d_ws, size_t ws_size,
                              hipStream_t stream) {
  const float* inp   = (const float*)d_in[0];
  const float* convw = (const float*)d_in[1];
  const float* convb = (const float*)d_in[2];
  float* out = (float*)d_out;
  char* ws = (char*)d_ws;

  u16* x1h = (u16*)(ws);                   // f16
  u16* x1T = (u16*)(ws + 16777216L);       // f16, transposed
  u16* inF = (u16*)(ws + 33554432L);       // f16 conv input
  u16* wT  = (u16*)(ws + 50331648L);       // f16 transposed weights

  k_prep<<<10496, 256, 0, stream>>>(inp, inF, convw, wT);
  k_conv<<<512, 256, 0, stream>>>(inF, wT, convb, x1h);
  k_trans<<<2048, 256, 0, stream>>>(x1h, x1T);
  k_flash7<<<512, 256, 0, stream>>>(x1h, x1T, inp, out);
}

// Round 24
// 275.524 us; speedup vs baseline: 1.0565x; 1.0565x over previous
//
#include <hip/hip_runtime.h>
#include <hip/hip_bf16.h>

typedef __attribute__((ext_vector_type(4))) float f32x4;
typedef __attribute__((ext_vector_type(8))) _Float16 f16x8; // MFMA f16 A/B frag
typedef unsigned short u16;

#define NB 8
#define NE 256
#define NN 4096
#define SD 64

__device__ __forceinline__ void gload_lds16(const void* g, void* l) {
  __builtin_amdgcn_global_load_lds((const __attribute__((address_space(1))) void*)g,
                                   (__attribute__((address_space(3))) void*)l, 16, 0, 0);
}
__device__ __forceinline__ float fexp2(float x) {
#if __has_builtin(__builtin_amdgcn_exp2f)
  return __builtin_amdgcn_exp2f(x);
#else
  return exp2f(x);
#endif
}

// ------- merged prep: f32->f16 input convert (bid<8192) + weight convert/transpose -------
__global__ __launch_bounds__(256) void k_prep(const float* __restrict__ x, u16* __restrict__ outF,
                                              const float* __restrict__ w, u16* __restrict__ wT) {
  int bid = blockIdx.x;
  int tid = threadIdx.x;
  if (bid < 8192) {
    int i = bid * 256 + tid;                    // float4 index < 2097152
    float4 v = reinterpret_cast<const float4*>(x)[i];
    ushort4 o;
    o.x = __builtin_bit_cast(u16, (_Float16)v.x);
    o.y = __builtin_bit_cast(u16, (_Float16)v.y);
    o.z = __builtin_bit_cast(u16, (_Float16)v.z);
    o.w = __builtin_bit_cast(u16, (_Float16)v.w);
    reinterpret_cast<ushort4*>(outF)[i] = o;
  } else {
    int i = (bid - 8192) * 256 + tid;           // < 9*256*256 = 589824
    int t = i >> 16;
    int r = i & 65535;
    int ei = r >> 8, eo = r & 255;
    int o = (t << 16) + (eo << 8) + ei;
    wT[o] = __builtin_bit_cast(u16, (_Float16)w[i]);
  }
}

// ---------------- conv 3x3 implicit GEMM, f16, halo-staged A (R14-exact, proven) ----------------
__global__ __launch_bounds__(256, 2) void k_conv(const u16* __restrict__ inF,
                                                 const u16* __restrict__ wT,
                                                 const float* __restrict__ bias,
                                                 u16* __restrict__ x1h) {
  __shared__ u16 Ahalo[264 * 64];               // 33 chunks of 1KB (slot = chunk*8 + lane>>3)
  __shared__ u16 BhL[2][128 * 64];              // B dbuf 2x16KB, swz ((eo&7)<<4)
  int b = blockIdx.x >> 6;
  int rem = blockIdx.x & 63;
  int mt = rem >> 1, et = rem & 1;
  int h0 = mt << 1;
  int tid = threadIdx.x;
  int wid = tid >> 6, lane = tid & 63;
  int wr = wid >> 1, wc = wid & 1;
  int r = lane & 15, g = lane >> 4;
  f32x4 acc[4][4];
#pragma unroll
  for (int i = 0; i < 4; ++i)
#pragma unroll
    for (int j = 0; j < 4; ++j) acc[i][j] = (f32x4){0.f, 0.f, 0.f, 0.f};
  const long ibase = (long)b * NN * NE;

  const int bsw = ((((lane & 7) << 4) ^ (((lane >> 3) & 7) << 4)) >> 1);  // f16 units
  long bSrc[4];
#pragma unroll
  for (int i = 0; i < 4; ++i) {
    int c = wid * 4 + i;
    int eo = c * 8 + (lane >> 3);
    bSrc[i] = (long)(et * 128 + eo) * 256 + bsw;
  }
  int aHalo[9];
  const u16* aSrc[9];
#pragma unroll
  for (int j = 0; j < 9; ++j) {
    int c = wid + 4 * j;
    int slot = c * 8 + (lane >> 3);
    int hr = slot >= 198 ? 3 : (slot >= 132 ? 2 : (slot >= 66 ? 1 : 0));
    int hc = slot - hr * 66;
    int ir = h0 - 1 + hr, ic = hc - 1;
    aHalo[j] = ((unsigned)ir >= 64u) | ((unsigned)ic >= 64u);
    int irc = min(max(ir, 0), 63), icc = min(max(ic, 0), 63);
    int c8s = (lane & 7) ^ (slot & 7);          // pre-swizzled ei chunk
    aSrc[j] = inF + ibase + ((long)(irc * 64 + icc) << 8) + c8s * 8;
  }

  // prologue: B(0,0) -> buf0
#pragma unroll
  for (int i = 0; i < 4; ++i)
    gload_lds16(wT + bSrc[i], (char*)BhL[0] + (wid * 4 + i) * 1024);

#pragma unroll 1
  for (int kc = 0; kc < 4; ++kc) {
    __builtin_amdgcn_s_barrier();               // all prev-kc A reads done
#pragma unroll
    for (int j = 0; j < 9; ++j) {
      int c = wid + 4 * j;
      if (c < 33)                               // wave-uniform
        gload_lds16(aSrc[j] + kc * 64, (char*)Ahalo + c * 1024);
    }
    asm volatile("s_waitcnt vmcnt(0)" ::: "memory");
#pragma unroll
    for (int j = 0; j < 9; ++j) {
      int c = wid + 4 * j;
      if (c < 33 && aHalo[j])
        *reinterpret_cast<float4*>((char*)Ahalo + c * 1024 + (lane << 4)) =
            make_float4(0.f, 0.f, 0.f, 0.f);
    }
    asm volatile("s_waitcnt lgkmcnt(0)" ::: "memory");
    __builtin_amdgcn_s_barrier();               // A(kc) visible

#pragma unroll 1
    for (int t = 0; t < 9; ++t) {
      int gidx = kc * 9 + t;
      if (t > 0) {
        asm volatile("s_waitcnt vmcnt(0)" ::: "memory");
        __builtin_amdgcn_s_barrier();
      }
      if (gidx < 35) {
        int nt = t + 1 == 9 ? 0 : t + 1;
        int nkc = t + 1 == 9 ? kc + 1 : kc;
        long tkoff = ((long)nt << 16) + nkc * 64;
        char* dstB = (char*)BhL[(gidx + 1) & 1];
#pragma unroll
        for (int i = 0; i < 4; ++i)
          gload_lds16(wT + tkoff + bSrc[i], dstB + (wid * 4 + i) * 1024);
      }
      const u16* BB = BhL[gidx & 1];
      int dy = t / 3 - 1, dx = t % 3 - 1;
      int abase = (wr + 1 + dy) * 66 + 1 + dx;  // + mi*16 + r
#pragma unroll
      for (int ks = 0; ks < 2; ++ks) {
        int c8 = ks * 4 + g;
        f16x8 ah[4], bh[4];
#pragma unroll
        for (int mi = 0; mi < 4; ++mi) {
          int slot = abase + mi * 16 + r;
          int abyte = (slot << 7) + ((c8 << 4) ^ ((slot & 7) << 4));
          ah[mi] = *reinterpret_cast<const f16x8*>(reinterpret_cast<const char*>(Ahalo) + abyte);
        }
#pragma unroll
        for (int ni = 0; ni < 4; ++ni) {
          int col = wc * 64 + ni * 16 + r;
          int bbyte = (col << 7) + ((c8 << 4) ^ ((r & 7) << 4));
          bh[ni] = *reinterpret_cast<const f16x8*>(reinterpret_cast<const char*>(BB) + bbyte);
        }
#pragma unroll
        for (int mi = 0; mi < 4; ++mi)
#pragma unroll
          for (int ni = 0; ni < 4; ++ni)
            acc[mi][ni] = __builtin_amdgcn_mfma_f32_16x16x32_f16(ah[mi], bh[ni], acc[mi][ni], 0, 0, 0);
      }
    }
  }
#pragma unroll
  for (int mi = 0; mi < 4; ++mi)
#pragma unroll
    for (int ni = 0; ni < 4; ++ni) {
      int eo = et * 128 + wc * 64 + ni * 16 + r;
      float bz = bias[eo];
#pragma unroll
      for (int i = 0; i < 4; ++i) {
        int pix = mt * 128 + wr * 64 + mi * 16 + g * 4 + i;
        float v = acc[mi][ni][i] + bz;
        long o = ibase + (long)pix * NE + eo;
        x1h[o] = __builtin_bit_cast(u16, (_Float16)v);
      }
    }
}

// ---------------- transpose x1h[b][m][e] -> x1T[b][e][m] ----------------
__global__ __launch_bounds__(256) void k_trans(const u16* __restrict__ x1h, u16* __restrict__ x1T) {
  __shared__ u16 T[64][72];
  int bid = blockIdx.x;
  int b = bid >> 8, rem = bid & 255;
  int mt = rem >> 2, et = rem & 3;
  int tid = threadIdx.x;
  for (int c = tid; c < 512; c += 256) {
    int rr = c >> 3, c8 = c & 7;
    *reinterpret_cast<float4*>(&T[rr][c8 * 8]) =
        *reinterpret_cast<const float4*>(x1h + ((long)b * NN + mt * 64 + rr) * NE + et * 64 + c8 * 8);
  }
  __syncthreads();
  for (int c = tid; c < 512; c += 256) {
    int er = c >> 3, m8 = c & 7;
    union { u16 u[8]; float4 v; } p;
#pragma unroll
    for (int j = 0; j < 8; ++j) p.u[j] = T[m8 * 8 + j][er];
    *reinterpret_cast<float4*>(x1T + ((long)b * NE + et * 64 + er) * NN + mt * 64 + m8 * 8) = p.v;
  }
}

// ---------------- fused flash attention, f16, 16x16 MFMA, EARLY-ISSUE staging (R22-exact, best) ----------------
// grid 512 = 8b x 64 q-tiles of 64 rows (phys&7 = batch = XCD). block 256 = 4 waves;
// wave owns 16 q-rows x FULL 256 e — no QK duplication. V(it)+K(it+1) issued right
// after bar1 (safety established there); vmcnt(4)+bar2 before PV. LDS 48KB:
// K dbuf 2x16KB @0, V single 16KB @32K.
// K swz: byte ^ ((row&15)<<4) in 512B rows. V swz: bit6 row-pair swap + ((e&3)<<4).
__global__ __launch_bounds__(256, 3) void k_flash7(const u16* __restrict__ x1h16,
                                                   const u16* __restrict__ x1T,
                                                   const float* __restrict__ inp,
                                                   float* __restrict__ out) {
  __shared__ char LDS[49152];
  int phys = blockIdx.x;
  int b = phys & 7;                             // batch == XCD
  int qt = phys >> 3;                           // q-tile of 64 rows (0..63)
  int tid = threadIdx.x, wid = tid >> 6, lane = tid & 63;
  int l15 = lane & 15, g4 = (lane >> 4) & 3;
  const long bN = (long)b << 12;
  const long vtb = (long)b << 20;

  // Q (f16): B-frag of S^T=mfma(K,Q): col=l15=q-row, k=g4*8+j; pre-scaled by log2e
  const long qrow = bN + qt * 64 + wid * 16 + l15;
  f16x8 qh[8];
#pragma unroll
  for (int kc = 0; kc < 8; ++kc) {
    qh[kc] = *reinterpret_cast<const f16x8*>(x1h16 + (qrow << 8) + kc * 32 + g4 * 8);
#pragma unroll
    for (int j = 0; j < 8; ++j)
      qh[kc][j] = (_Float16)((float)qh[kc][j] * 1.44269504f);
  }

  f32x4 o16[16];                                // O[16q][256e]: q=g4*4+i, e=et*16+l15
#pragma unroll
  for (int et = 0; et < 16; ++et) o16[et] = (f32x4){0.f, 0.f, 0.f, 0.f};
  float mrow = -1.0e30f, lrow = 0.f;

  // ---- staging pointers (kv0 = 0): K 16 chunks (4/thread), V 16 chunks (4/thread) ----
  const u16* kS[4];
  const u16* vS[4];
  int off[4];
#pragma unroll
  for (int i = 0; i < 4; ++i) {
    int c = wid * 4 + i;
    off[i] = c << 10;
    int kr = c * 2 + (lane >> 5);
    int kcolb = ((lane & 31) << 4) ^ ((kr & 15) << 4);
    kS[i] = x1h16 + ((bN + kr) << 8) + (kcolb >> 1);
    int rp = c * 16 + (lane >> 2);
    int e = rp ^ ((rp >> 2) & 1);               // involutive row-pair swap (bit6)
    int vcolb = ((lane & 3) << 4) ^ ((e & 3) << 4);
    vS[i] = x1T + vtb + ((long)e << 12) + (vcolb >> 1);
  }

  // per-lane constant V-read base: row l15 within e-tile + swizzles; +et*1024 per tile
  const int vbase = ((l15 << 6) ^ ((l15 & 4) << 4)) + ((g4 * 16) ^ ((l15 & 3) << 4));
  const int kxor = l15 << 4;
  // re-fragment shuffle sources: src_a = bit4(lane)*32 + l15; src_b = src_a+16; sel by bit5
  const int srcA = ((lane >> 4) & 1) * 32 + l15;
  const int srcB = srcA + 16;
  const bool hiHalf = (lane & 32) != 0;

  // ---- prologue: stage K(0) -> Kbuf0 ----
#pragma unroll
  for (int i = 0; i < 4; ++i) { gload_lds16(kS[i], LDS + off[i]); kS[i] += 8192; }

#pragma unroll 1
  for (int it = 0; it < 128; ++it) {
    const char* KB = LDS + (it & 1) * 16384;
    char* VB = LDS + 32768;

    asm volatile("s_waitcnt vmcnt(0)" ::: "memory");   // K(it) landed
    __builtin_amdgcn_s_barrier();                      // bar1: PV(it-1)/QK(it-1) done
    __builtin_amdgcn_sched_barrier(0);

    // ---- EARLY ISSUE: V(it) into single V buf, then K(it+1) (safety from bar1) ----
#pragma unroll
    for (int i = 0; i < 4; ++i) { gload_lds16(vS[i], VB + off[i]); vS[i] += 32; }
    if (it < 127) {
      char* KD = LDS + ((it + 1) & 1) * 16384;
#pragma unroll
      for (int i = 0; i < 4; ++i) { gload_lds16(kS[i], KD + off[i]); kS[i] += 8192; }
    }

    // ---- S^T = K.Q : 2 kv-subtiles x 8 k-chunks = 16 MFMA, 2 chains ----
    f32x4 st0 = (f32x4){0.f, 0.f, 0.f, 0.f}, st1 = st0;
    int krow0 = l15 << 9, krow1 = (16 + l15) << 9;
    __builtin_amdgcn_s_setprio(1);
#pragma unroll
    for (int kc = 0; kc < 8; ++kc) {
      int kb = (kc * 64 + g4 * 16) ^ kxor;
      f16x8 k0 = *reinterpret_cast<const f16x8*>(KB + krow0 + kb);
      f16x8 k1 = *reinterpret_cast<const f16x8*>(KB + krow1 + kb);
      st0 = __builtin_amdgcn_mfma_f32_16x16x32_f16(k0, qh[kc], st0, 0, 0, 0);
      st1 = __builtin_amdgcn_mfma_f32_16x16x32_f16(k1, qh[kc], st1, 0, 0, 0);
    }
    __builtin_amdgcn_s_setprio(0);

    // ---- online softmax in log2 domain; q = l15, kv = s*16 + g4*4 + i ----
    float tmax = fmaxf(fmaxf(fmaxf(st0[0], st0[1]), fmaxf(st0[2], st0[3])),
                       fmaxf(fmaxf(st1[0], st1[1]), fmaxf(st1[2], st1[3])));
    tmax = fmaxf(tmax, __shfl_xor(tmax, 16));
    tmax = fmaxf(tmax, __shfl_xor(tmax, 32));
    if (!__all(tmax <= mrow + 11.54f)) {        // defer-max (T13), 8*log2e
      float mnew = fmaxf(mrow, tmax);
      float alpha = fexp2(mrow - mnew);
      lrow *= alpha;
      float ar[4];
#pragma unroll
      for (int i = 0; i < 4; ++i) ar[i] = __shfl(alpha, g4 * 4 + i);
#pragma unroll
      for (int et = 0; et < 16; ++et)
#pragma unroll
        for (int i = 0; i < 4; ++i) o16[et][i] *= ar[i];
      mrow = mnew;
    }
#pragma unroll
    for (int i = 0; i < 4; ++i) { st0[i] = fexp2(st0[i] - mrow); st1[i] = fexp2(st1[i] - mrow); }
    float psum = (st0[0] + st0[1]) + (st0[2] + st0[3]) + (st1[0] + st1[1]) + (st1[2] + st1[3]);
    psum += __shfl_xor(psum, 16);
    psum += __shfl_xor(psum, 32);
    lrow += psum;

    // ---- P -> f16 words; re-fragment to PV A-frag (kv = g'*8+j) via 8 shfl + selects ----
    int W0, W1, W2, W3;
    {
      unsigned a0 = __builtin_bit_cast(u16, (_Float16)st0[0]);
      unsigned a1 = __builtin_bit_cast(u16, (_Float16)st0[1]);
      unsigned a2 = __builtin_bit_cast(u16, (_Float16)st0[2]);
      unsigned a3 = __builtin_bit_cast(u16, (_Float16)st0[3]);
      unsigned b0 = __builtin_bit_cast(u16, (_Float16)st1[0]);
      unsigned b1 = __builtin_bit_cast(u16, (_Float16)st1[1]);
      unsigned b2 = __builtin_bit_cast(u16, (_Float16)st1[2]);
      unsigned b3 = __builtin_bit_cast(u16, (_Float16)st1[3]);
      W0 = (int)(a0 | (a1 << 16)); W1 = (int)(a2 | (a3 << 16));
      W2 = (int)(b0 | (b1 << 16)); W3 = (int)(b2 | (b3 << 16));
    }
    union PU { int w[4]; f16x8 v; } pa;
    {
      int u0a = __shfl(W0, srcA), u2a = __shfl(W2, srcA);
      int u1a = __shfl(W1, srcA), u3a = __shfl(W3, srcA);
      int u0b = __shfl(W0, srcB), u2b = __shfl(W2, srcB);
      int u1b = __shfl(W1, srcB), u3b = __shfl(W3, srcB);
      pa.w[0] = hiHalf ? u2a : u0a;
      pa.w[1] = hiHalf ? u3a : u1a;
      pa.w[2] = hiHalf ? u2b : u0b;
      pa.w[3] = hiHalf ? u3b : u1b;
    }

    // ---- wait V(it) (K(it+1) still in flight), bar2, then PV: 16 e-tiles ----
    if (it < 127) {
      asm volatile("s_waitcnt vmcnt(4)" ::: "memory");
    } else {
      asm volatile("s_waitcnt vmcnt(0)" ::: "memory");
    }
    __builtin_amdgcn_s_barrier();
    __builtin_amdgcn_sched_barrier(0);

    __builtin_amdgcn_s_setprio(1);
#pragma unroll
    for (int et = 0; et < 16; ++et) {
      f16x8 v = *reinterpret_cast<const f16x8*>(VB + vbase + et * 1024);
      o16[et] = __builtin_amdgcn_mfma_f32_16x16x32_f16(pa.v, v, o16[et], 0, 0, 0);
    }
    __builtin_amdgcn_s_setprio(0);
  }

  // ---- epilogue: /(16*l) * inp; O: q=g4*4+i, e=et*16+l15 ----
  float linv = 1.0f / (16.0f * lrow);
  float lr[4];
#pragma unroll
  for (int i = 0; i < 4; ++i) lr[i] = __shfl(linv, g4 * 4 + i);
  const long ob = (bN + qt * 64 + wid * 16) << 8;
#pragma unroll
  for (int et = 0; et < 16; ++et)
#pragma unroll
    for (int i = 0; i < 4; ++i) {
      long off2 = ob + ((long)(g4 * 4 + i) << 8) + et * 16 + l15;
      out[off2] = o16[et][i] * lr[i] * inp[off2];
    }
}

// ---------------- host ----------------
// ws layout (bytes):
//   [0,   16M)  x1h f16
//   [16M, 32M)  x1T f16
//   [32M, 48M)  inF f16 (conv temp)
//   [48M, +1.2M) wT f16 (conv temp)
extern "C" void kernel_launch(void* const* d_in, const int* in_sizes, int n_in,
                              void* d_out, int out_size, void* d_ws, size_t ws_size,
                              hipStream_t stream) {
  const float* inp   = (const float*)d_in[0];
  const float* convw = (const float*)d_in[1];
  const float* convb = (const float*)d_in[2];
  float* out = (float*)d_out;
  char* ws = (char*)d_ws;

  u16* x1h = (u16*)(ws);                   // f16
  u16* x1T = (u16*)(ws + 16777216L);       // f16, transposed
  u16* inF = (u16*)(ws + 33554432L);       // f16 conv input
  u16* wT  = (u16*)(ws + 50331648L);       // f16 transposed weights

  k_prep<<<10496, 256, 0, stream>>>(inp, inF, convw, wT);
  k_conv<<<512, 256, 0, stream>>>(inF, wT, convb, x1h);
  k_trans<<<2048, 256, 0, stream>>>(x1h, x1T);
  k_flash7<<<512, 256, 0, stream>>>(x1h, x1T, inp, out);
}